// Round 1
// baseline (805.140 us; speedup 1.0000x reference)
//
#include <hip/hip_runtime.h>
#include <math.h>

#define DF 128  // feature dim (both in and out)

// ---------------- degree histogram ----------------
__global__ __launch_bounds__(256) void k_zero(int* __restrict__ deg, int N) {
    int n = blockIdx.x * 256 + threadIdx.x;
    if (n < N) deg[n] = 0;
}

__global__ __launch_bounds__(256) void k_hist(const int* __restrict__ col, int* deg, int E) {
    int i = blockIdx.x * 256 + threadIdx.x;
    int e = i * 4;
    if (e + 3 < E) {
        int4 c4 = *(const int4*)(col + e);
        atomicAdd(&deg[c4.x], 1);
        atomicAdd(&deg[c4.y], 1);
        atomicAdd(&deg[c4.z], 1);
        atomicAdd(&deg[c4.w], 1);
    } else {
        for (; e < E; ++e) atomicAdd(&deg[col[e]], 1);
    }
}

// ---------------- exclusive scan (3-phase, N <= 512*256) ----------------
__global__ __launch_bounds__(256) void k_scanA(const int* __restrict__ deg,
                                               int* __restrict__ partials,
                                               int* __restrict__ blockSums, int N) {
    __shared__ int tmp[256];
    int tid = threadIdx.x;
    int n = blockIdx.x * 256 + tid;
    int v = (n < N) ? deg[n] : 0;
    tmp[tid] = v;
    __syncthreads();
    for (int off = 1; off < 256; off <<= 1) {
        int t = (tid >= off) ? tmp[tid - off] : 0;
        __syncthreads();
        tmp[tid] += t;
        __syncthreads();
    }
    if (tid == 255) blockSums[blockIdx.x] = tmp[255];
    if (n < N) partials[n] = tmp[tid] - v;  // exclusive within block
}

__global__ __launch_bounds__(512) void k_scanB(int* __restrict__ blockSums, int nb) {
    __shared__ int tmp[512];
    int tid = threadIdx.x;
    int v = (tid < nb) ? blockSums[tid] : 0;
    tmp[tid] = v;
    __syncthreads();
    for (int off = 1; off < 512; off <<= 1) {
        int t = (tid >= off) ? tmp[tid - off] : 0;
        __syncthreads();
        tmp[tid] += t;
        __syncthreads();
    }
    if (tid < nb) blockSums[tid] = tmp[tid] - v;  // exclusive block offsets
}

__global__ __launch_bounds__(256) void k_scanC(int* __restrict__ offsets,
                                               const int* __restrict__ blockSums,
                                               int* __restrict__ cursor,
                                               const int* __restrict__ deg,
                                               float* __restrict__ dinv, int N) {
    int n = blockIdx.x * 256 + threadIdx.x;
    if (n >= N) return;
    int o = offsets[n] + blockSums[n >> 8];
    offsets[n] = o;
    cursor[n] = o;
    dinv[n] = 1.0f / sqrtf((float)(deg[n] + 1));  // +1 self-loop
}

// ---------------- CSR fill (position scatter) ----------------
__global__ __launch_bounds__(256) void k_fill(const int* __restrict__ edge, int* cursor,
                                              int* __restrict__ ssrc, int E) {
    int i = blockIdx.x * 256 + threadIdx.x;
    int e = i * 4;
    if (e + 3 < E) {
        int4 r4 = *(const int4*)(edge + e);
        int4 c4 = *(const int4*)(edge + E + e);
        ssrc[atomicAdd(&cursor[c4.x], 1)] = r4.x;
        ssrc[atomicAdd(&cursor[c4.y], 1)] = r4.y;
        ssrc[atomicAdd(&cursor[c4.z], 1)] = r4.z;
        ssrc[atomicAdd(&cursor[c4.w], 1)] = r4.w;
    } else {
        for (; e < E; ++e) ssrc[atomicAdd(&cursor[edge[E + e]], 1)] = edge[e];
    }
}

// ---------------- GEMM y = (x @ W) * dinv[row], W staged in LDS ----------------
__device__ inline void fma4(float4& acc, const float4 xv, const float4 w0,
                            const float4 w1, const float4 w2, const float4 w3) {
    acc.x = fmaf(xv.x, w0.x, fmaf(xv.y, w1.x, fmaf(xv.z, w2.x, fmaf(xv.w, w3.x, acc.x))));
    acc.y = fmaf(xv.x, w0.y, fmaf(xv.y, w1.y, fmaf(xv.z, w2.y, fmaf(xv.w, w3.y, acc.y))));
    acc.z = fmaf(xv.x, w0.z, fmaf(xv.y, w1.z, fmaf(xv.z, w2.z, fmaf(xv.w, w3.z, acc.z))));
    acc.w = fmaf(xv.x, w0.w, fmaf(xv.y, w1.w, fmaf(xv.z, w2.w, fmaf(xv.w, w3.w, acc.w))));
}

__global__ __launch_bounds__(256) void k_gemm(const float* __restrict__ x,
                                              const float* __restrict__ W,
                                              const float* __restrict__ dinv,
                                              float* __restrict__ y, int N) {
    __shared__ float Ws[DF * DF];  // 64 KiB -> 2 blocks/CU
    for (int i = threadIdx.x; i < DF * DF / 4; i += 256)
        ((float4*)Ws)[i] = ((const float4*)W)[i];
    __syncthreads();

    const int fg = (threadIdx.x & 31) * 4;  // feature start [0,128)
    const int rl = (threadIdx.x >> 5) * 4;  // 8 groups x 4 rows = 32 rows/block

    for (int rowBase = blockIdx.x * 32; rowBase < N; rowBase += gridDim.x * 32) {
        int r0 = rowBase + rl;
        // clamp for tail safety (N%32==0 here, but be safe)
        int c0 = min(r0 + 0, N - 1), c1 = min(r0 + 1, N - 1);
        int c2 = min(r0 + 2, N - 1), c3 = min(r0 + 3, N - 1);
        const float4* x0 = (const float4*)(x + (size_t)c0 * DF);
        const float4* x1 = (const float4*)(x + (size_t)c1 * DF);
        const float4* x2 = (const float4*)(x + (size_t)c2 * DF);
        const float4* x3 = (const float4*)(x + (size_t)c3 * DF);
        float4 a0 = {0, 0, 0, 0}, a1 = {0, 0, 0, 0}, a2 = {0, 0, 0, 0}, a3 = {0, 0, 0, 0};
        for (int k4 = 0; k4 < DF / 4; ++k4) {
            float4 xv0 = x0[k4], xv1 = x1[k4], xv2 = x2[k4], xv3 = x3[k4];
            int k = k4 * 4;
            float4 w0 = *(const float4*)(Ws + (k + 0) * DF + fg);
            float4 w1 = *(const float4*)(Ws + (k + 1) * DF + fg);
            float4 w2 = *(const float4*)(Ws + (k + 2) * DF + fg);
            float4 w3 = *(const float4*)(Ws + (k + 3) * DF + fg);
            fma4(a0, xv0, w0, w1, w2, w3);
            fma4(a1, xv1, w0, w1, w2, w3);
            fma4(a2, xv2, w0, w1, w2, w3);
            fma4(a3, xv3, w0, w1, w2, w3);
        }
        float d0 = dinv[c0], d1 = dinv[c1], d2 = dinv[c2], d3 = dinv[c3];
        a0.x *= d0; a0.y *= d0; a0.z *= d0; a0.w *= d0;
        a1.x *= d1; a1.y *= d1; a1.z *= d1; a1.w *= d1;
        a2.x *= d2; a2.y *= d2; a2.z *= d2; a2.w *= d2;
        a3.x *= d3; a3.y *= d3; a3.z *= d3; a3.w *= d3;
        if (r0 + 0 < N) *(float4*)(y + (size_t)(r0 + 0) * DF + fg) = a0;
        if (r0 + 1 < N) *(float4*)(y + (size_t)(r0 + 1) * DF + fg) = a1;
        if (r0 + 2 < N) *(float4*)(y + (size_t)(r0 + 2) * DF + fg) = a2;
        if (r0 + 3 < N) *(float4*)(y + (size_t)(r0 + 3) * DF + fg) = a3;
    }
}

// ---------------- gather-aggregate: one wave per target node ----------------
__global__ __launch_bounds__(256) void k_gather(const float* __restrict__ y,
                                                const int* __restrict__ ssrc,
                                                const int* __restrict__ offsets,
                                                const int* __restrict__ deg,
                                                const float* __restrict__ dinv,
                                                const float* __restrict__ b,
                                                float* __restrict__ out, int N) {
    int wave = (blockIdx.x * 256 + threadIdx.x) >> 6;  // 4 waves/block = 4 nodes
    int lane = threadIdx.x & 63;
    if (wave >= N) return;
    int c = wave;
    int start = offsets[c];
    int d = deg[c];

    // self-loop term: acc starts at y[c]
    float2 acc = *(const float2*)(y + (size_t)c * DF + lane * 2);

    int i = 0;
    for (; i + 2 <= d; i += 2) {
        int r0 = ssrc[start + i];
        int r1 = ssrc[start + i + 1];
        float2 v0 = *(const float2*)(y + (size_t)r0 * DF + lane * 2);
        float2 v1 = *(const float2*)(y + (size_t)r1 * DF + lane * 2);
        acc.x += v0.x + v1.x;
        acc.y += v0.y + v1.y;
    }
    if (i < d) {
        int r0 = ssrc[start + i];
        float2 v0 = *(const float2*)(y + (size_t)r0 * DF + lane * 2);
        acc.x += v0.x;
        acc.y += v0.y;
    }

    float dv = dinv[c];
    float2 bb = *(const float2*)(b + lane * 2);
    float2 o;
    o.x = fmaxf(fmaf(dv, acc.x, bb.x), 0.0f);
    o.y = fmaxf(fmaf(dv, acc.y, bb.y), 0.0f);
    *(float2*)(out + (size_t)c * DF + lane * 2) = o;
}

extern "C" void kernel_launch(void* const* d_in, const int* in_sizes, int n_in,
                              void* d_out, int out_size, void* d_ws, size_t ws_size,
                              hipStream_t stream) {
    const float* x    = (const float*)d_in[0];
    const int*   edge = (const int*)d_in[1];   // [2, E] flat: rows then cols
    const float* W    = (const float*)d_in[2];
    const float* b    = (const float*)d_in[3];
    float*       out  = (float*)d_out;

    const int N = in_sizes[0] / DF;   // 100000
    const int E = in_sizes[1] / 2;    // 3200000

    // workspace layout (all 4B types; base is 16B-aligned)
    float* y         = (float*)d_ws;            // N*128 f32 (51.2 MB)
    int*   deg       = (int*)(y + (size_t)N * DF);
    float* dinv      = (float*)(deg + N);
    int*   offsets   = (int*)(dinv + N);
    int*   cursor    = offsets + N;
    int*   blockSums = cursor + N;              // 1024 slots
    int*   ssrc      = blockSums + 1024;        // E ints (12.8 MB)

    const int nbN = (N + 255) / 256;            // 391 (<=512 required by scanB)
    const int nbE4 = (E / 4 + 255) / 256;

    k_zero<<<nbN, 256, 0, stream>>>(deg, N);
    k_hist<<<nbE4 + 1, 256, 0, stream>>>(edge + E, deg, E);
    k_scanA<<<nbN, 256, 0, stream>>>(deg, offsets, blockSums, N);
    k_scanB<<<1, 512, 0, stream>>>(blockSums, nbN);
    k_scanC<<<nbN, 256, 0, stream>>>(offsets, blockSums, cursor, deg, dinv, N);
    k_fill<<<nbE4 + 1, 256, 0, stream>>>(edge, cursor, ssrc, E);
    k_gemm<<<(N + 31) / 32, 256, 0, stream>>>(x, W, dinv, y, N);
    k_gather<<<(N + 3) / 4, 256, 0, stream>>>(y, ssrc, offsets, deg, dinv, b, out, N);
}

// Round 2
// 497.453 us; speedup vs baseline: 1.6185x; 1.6185x over previous
//
#include <hip/hip_runtime.h>
#include <hip/hip_bf16.h>
#include <math.h>

#define DF 128  // feature dim (both in and out)

typedef __hip_bfloat16 bf16;
typedef __hip_bfloat162 bf16x2;

// ---------------- zero degree array ----------------
__global__ __launch_bounds__(256) void k_zero(int* __restrict__ deg, int N) {
    int n = blockIdx.x * 256 + threadIdx.x;
    if (n < N) deg[n] = 0;
}

// ---------------- degree histogram + per-edge rank ----------------
// rank[e] = position of edge e among edges sharing the same target.
// This is the ONLY atomic pass; k_fill becomes atomic-free.
__global__ __launch_bounds__(256) void k_hist(const int* __restrict__ col, int* deg,
                                              int* __restrict__ rank, int E) {
    int i = blockIdx.x * 256 + threadIdx.x;
    int e = i * 4;
    if (e + 3 < E) {
        int4 c4 = *(const int4*)(col + e);
        int4 r;
        r.x = atomicAdd(&deg[c4.x], 1);
        r.y = atomicAdd(&deg[c4.y], 1);
        r.z = atomicAdd(&deg[c4.z], 1);
        r.w = atomicAdd(&deg[c4.w], 1);
        *(int4*)(rank + e) = r;  // coalesced
    } else {
        for (; e < E; ++e) rank[e] = atomicAdd(&deg[col[e]], 1);
    }
}

// ---------------- exclusive scan (3-phase, N <= 512*256) ----------------
__global__ __launch_bounds__(256) void k_scanA(const int* __restrict__ deg,
                                               int* __restrict__ partials,
                                               int* __restrict__ blockSums, int N) {
    __shared__ int tmp[256];
    int tid = threadIdx.x;
    int n = blockIdx.x * 256 + tid;
    int v = (n < N) ? deg[n] : 0;
    tmp[tid] = v;
    __syncthreads();
    for (int off = 1; off < 256; off <<= 1) {
        int t = (tid >= off) ? tmp[tid - off] : 0;
        __syncthreads();
        tmp[tid] += t;
        __syncthreads();
    }
    if (tid == 255) blockSums[blockIdx.x] = tmp[255];
    if (n < N) partials[n] = tmp[tid] - v;  // exclusive within block
}

__global__ __launch_bounds__(512) void k_scanB(int* __restrict__ blockSums, int nb) {
    __shared__ int tmp[512];
    int tid = threadIdx.x;
    int v = (tid < nb) ? blockSums[tid] : 0;
    tmp[tid] = v;
    __syncthreads();
    for (int off = 1; off < 512; off <<= 1) {
        int t = (tid >= off) ? tmp[tid - off] : 0;
        __syncthreads();
        tmp[tid] += t;
        __syncthreads();
    }
    if (tid < nb) blockSums[tid] = tmp[tid] - v;  // exclusive block offsets
}

__global__ __launch_bounds__(256) void k_scanC(int* __restrict__ offsets,
                                               const int* __restrict__ blockSums,
                                               const int* __restrict__ deg,
                                               float* __restrict__ dinv, int N) {
    int n = blockIdx.x * 256 + threadIdx.x;
    if (n >= N) return;
    offsets[n] = offsets[n] + blockSums[n >> 8];
    dinv[n] = 1.0f / sqrtf((float)(deg[n] + 1));  // +1 self-loop
}

// ---------------- CSR fill (atomic-free position scatter) ----------------
__global__ __launch_bounds__(256) void k_fill(const int* __restrict__ edge,
                                              const int* __restrict__ offsets,
                                              const int* __restrict__ rank,
                                              int* __restrict__ ssrc, int E) {
    int i = blockIdx.x * 256 + threadIdx.x;
    int e = i * 4;
    if (e + 3 < E) {
        int4 r4 = *(const int4*)(edge + e);
        int4 c4 = *(const int4*)(edge + E + e);
        int4 k4 = *(const int4*)(rank + e);
        ssrc[offsets[c4.x] + k4.x] = r4.x;
        ssrc[offsets[c4.y] + k4.y] = r4.y;
        ssrc[offsets[c4.z] + k4.z] = r4.z;
        ssrc[offsets[c4.w] + k4.w] = r4.w;
    } else {
        for (; e < E; ++e) ssrc[offsets[edge[E + e]] + rank[e]] = edge[e];
    }
}

// ---------------- GEMM y = bf16((x @ W) * dinv[row]), W staged in LDS ----------------
__device__ inline void fma4(float4& acc, const float4 xv, const float4 w0,
                            const float4 w1, const float4 w2, const float4 w3) {
    acc.x = fmaf(xv.x, w0.x, fmaf(xv.y, w1.x, fmaf(xv.z, w2.x, fmaf(xv.w, w3.x, acc.x))));
    acc.y = fmaf(xv.x, w0.y, fmaf(xv.y, w1.y, fmaf(xv.z, w2.y, fmaf(xv.w, w3.y, acc.y))));
    acc.z = fmaf(xv.x, w0.z, fmaf(xv.y, w1.z, fmaf(xv.z, w2.z, fmaf(xv.w, w3.z, acc.z))));
    acc.w = fmaf(xv.x, w0.w, fmaf(xv.y, w1.w, fmaf(xv.z, w2.w, fmaf(xv.w, w3.w, acc.w))));
}

__device__ inline uint2 pack_bf16x4(float4 a) {
    union { uint2 u; bf16x2 h[2]; } p;
    p.h[0] = __float22bfloat162_rn(make_float2(a.x, a.y));
    p.h[1] = __float22bfloat162_rn(make_float2(a.z, a.w));
    return p.u;
}

__global__ __launch_bounds__(256) void k_gemm(const float* __restrict__ x,
                                              const float* __restrict__ W,
                                              const float* __restrict__ dinv,
                                              bf16* __restrict__ y, int N) {
    __shared__ float Ws[DF * DF];  // 64 KiB -> 2 blocks/CU
    for (int i = threadIdx.x; i < DF * DF / 4; i += 256)
        ((float4*)Ws)[i] = ((const float4*)W)[i];
    __syncthreads();

    const int fg = (threadIdx.x & 31) * 4;  // feature start [0,128)
    const int rl = (threadIdx.x >> 5) * 4;  // 8 groups x 4 rows = 32 rows/block

    for (int rowBase = blockIdx.x * 32; rowBase < N; rowBase += gridDim.x * 32) {
        int r0 = rowBase + rl;
        int c0 = min(r0 + 0, N - 1), c1 = min(r0 + 1, N - 1);
        int c2 = min(r0 + 2, N - 1), c3 = min(r0 + 3, N - 1);
        const float4* x0 = (const float4*)(x + (size_t)c0 * DF);
        const float4* x1 = (const float4*)(x + (size_t)c1 * DF);
        const float4* x2 = (const float4*)(x + (size_t)c2 * DF);
        const float4* x3 = (const float4*)(x + (size_t)c3 * DF);
        float4 a0 = {0, 0, 0, 0}, a1 = {0, 0, 0, 0}, a2 = {0, 0, 0, 0}, a3 = {0, 0, 0, 0};
        for (int k4 = 0; k4 < DF / 4; ++k4) {
            float4 xv0 = x0[k4], xv1 = x1[k4], xv2 = x2[k4], xv3 = x3[k4];
            int k = k4 * 4;
            float4 w0 = *(const float4*)(Ws + (k + 0) * DF + fg);
            float4 w1 = *(const float4*)(Ws + (k + 1) * DF + fg);
            float4 w2 = *(const float4*)(Ws + (k + 2) * DF + fg);
            float4 w3 = *(const float4*)(Ws + (k + 3) * DF + fg);
            fma4(a0, xv0, w0, w1, w2, w3);
            fma4(a1, xv1, w0, w1, w2, w3);
            fma4(a2, xv2, w0, w1, w2, w3);
            fma4(a3, xv3, w0, w1, w2, w3);
        }
        float d0 = dinv[c0], d1 = dinv[c1], d2 = dinv[c2], d3 = dinv[c3];
        a0.x *= d0; a0.y *= d0; a0.z *= d0; a0.w *= d0;
        a1.x *= d1; a1.y *= d1; a1.z *= d1; a1.w *= d1;
        a2.x *= d2; a2.y *= d2; a2.z *= d2; a2.w *= d2;
        a3.x *= d3; a3.y *= d3; a3.z *= d3; a3.w *= d3;
        if (r0 + 0 < N) *(uint2*)(y + (size_t)(r0 + 0) * DF + fg) = pack_bf16x4(a0);
        if (r0 + 1 < N) *(uint2*)(y + (size_t)(r0 + 1) * DF + fg) = pack_bf16x4(a1);
        if (r0 + 2 < N) *(uint2*)(y + (size_t)(r0 + 2) * DF + fg) = pack_bf16x4(a2);
        if (r0 + 3 < N) *(uint2*)(y + (size_t)(r0 + 3) * DF + fg) = pack_bf16x4(a3);
    }
}

// ---------------- gather-aggregate: one wave per target node ----------------
__global__ __launch_bounds__(256) void k_gather(const bf16x2* __restrict__ y,  // stride 64/row
                                                const int* __restrict__ ssrc,
                                                const int* __restrict__ offsets,
                                                const int* __restrict__ deg,
                                                const float* __restrict__ dinv,
                                                const float* __restrict__ b,
                                                float* __restrict__ out, int N) {
    int wave = (blockIdx.x * 256 + threadIdx.x) >> 6;  // 4 waves/block = 4 nodes
    int lane = threadIdx.x & 63;
    if (wave >= N) return;
    int c = wave;
    int start = offsets[c];
    int d = deg[c];

    // self-loop term: acc starts at y[c]
    float2 acc = __bfloat1622float2(y[(size_t)c * 64 + lane]);

    int i = 0;
    for (; i + 4 <= d; i += 4) {
        int r0 = ssrc[start + i + 0];
        int r1 = ssrc[start + i + 1];
        int r2 = ssrc[start + i + 2];
        int r3 = ssrc[start + i + 3];
        float2 v0 = __bfloat1622float2(y[(size_t)r0 * 64 + lane]);
        float2 v1 = __bfloat1622float2(y[(size_t)r1 * 64 + lane]);
        float2 v2 = __bfloat1622float2(y[(size_t)r2 * 64 + lane]);
        float2 v3 = __bfloat1622float2(y[(size_t)r3 * 64 + lane]);
        acc.x += (v0.x + v1.x) + (v2.x + v3.x);
        acc.y += (v0.y + v1.y) + (v2.y + v3.y);
    }
    for (; i < d; ++i) {
        int r0 = ssrc[start + i];
        float2 v0 = __bfloat1622float2(y[(size_t)r0 * 64 + lane]);
        acc.x += v0.x;
        acc.y += v0.y;
    }

    float dv = dinv[c];
    float2 bb = *(const float2*)(b + lane * 2);
    float2 o;
    o.x = fmaxf(fmaf(dv, acc.x, bb.x), 0.0f);
    o.y = fmaxf(fmaf(dv, acc.y, bb.y), 0.0f);
    *(float2*)(out + (size_t)c * DF + lane * 2) = o;
}

extern "C" void kernel_launch(void* const* d_in, const int* in_sizes, int n_in,
                              void* d_out, int out_size, void* d_ws, size_t ws_size,
                              hipStream_t stream) {
    const float* x    = (const float*)d_in[0];
    const int*   edge = (const int*)d_in[1];   // [2, E] flat: rows then cols
    const float* W    = (const float*)d_in[2];
    const float* b    = (const float*)d_in[3];
    float*       out  = (float*)d_out;

    const int N = in_sizes[0] / DF;   // 100000
    const int E = in_sizes[1] / 2;    // 3200000

    // workspace layout (base is 16B-aligned)
    bf16*  y         = (bf16*)d_ws;             // N*128 bf16 (25.6 MB)
    int*   deg       = (int*)(y + (size_t)N * DF);
    float* dinv      = (float*)(deg + N);
    int*   offsets   = (int*)(dinv + N);
    int*   blockSums = offsets + N;             // 1024 slots
    int*   rank      = blockSums + 1024;        // E ints (12.8 MB)
    int*   ssrc      = rank + E;                // E ints (12.8 MB)

    const int nbN = (N + 255) / 256;            // 391 (<=512 required by scanB)
    const int nbE4 = (E / 4 + 255) / 256;

    k_zero<<<nbN, 256, 0, stream>>>(deg, N);
    k_hist<<<nbE4 + 1, 256, 0, stream>>>(edge + E, deg, rank, E);
    k_scanA<<<nbN, 256, 0, stream>>>(deg, offsets, blockSums, N);
    k_scanB<<<1, 512, 0, stream>>>(blockSums, nbN);
    k_scanC<<<nbN, 256, 0, stream>>>(offsets, blockSums, deg, dinv, N);
    k_fill<<<nbE4 + 1, 256, 0, stream>>>(edge, offsets, rank, ssrc, E);
    k_gemm<<<(N + 31) / 32, 256, 0, stream>>>(x, W, dinv, y, N);
    k_gather<<<(N + 3) / 4, 256, 0, stream>>>((const bf16x2*)y, ssrc, offsets, deg, dinv, b, out, N);
}

// Round 3
// 382.028 us; speedup vs baseline: 2.1075x; 1.3021x over previous
//
#include <hip/hip_runtime.h>
#include <hip/hip_bf16.h>
#include <math.h>

#define DF 128           // feature dim (both in and out)
#define TILE_EDGES 16384 // edges per bin tile (P1/P3)
#define NPB 256          // nodes per bucket (bucket = col >> 8)
#define NB_MAX 512       // max buckets (supports N <= 131072)

typedef __hip_bfloat16 bf16;
typedef __hip_bfloat162 bf16x2;

// ---------------- P1: per-tile LDS histogram over buckets ----------------
// counts laid out bucket-major: counts[b*T + t]
__global__ __launch_bounds__(1024) void k_binc(const int* __restrict__ col,
                                               int* __restrict__ counts,
                                               int E, int T, int NB) {
    __shared__ int h[NB_MAX];
    int tid = threadIdx.x;
    for (int i = tid; i < NB; i += 1024) h[i] = 0;
    __syncthreads();
    int tileBase = blockIdx.x * TILE_EDGES;
    for (int j = 0; j < TILE_EDGES / 1024; ++j) {
        int e = tileBase + j * 1024 + tid;
        if (e < E) atomicAdd(&h[col[e] >> 8], 1);
    }
    __syncthreads();
    for (int b = tid; b < NB; b += 1024)
        counts[b * T + blockIdx.x] = h[b];
}

// ---------------- scan of counts (M = NB*T elements), 3-phase ----------------
__global__ __launch_bounds__(256) void k_scanA(int* __restrict__ data,
                                               int* __restrict__ blockSums, int M) {
    __shared__ int tmp[256];
    int tid = threadIdx.x;
    int n = blockIdx.x * 256 + tid;
    int v = (n < M) ? data[n] : 0;
    tmp[tid] = v;
    __syncthreads();
    for (int off = 1; off < 256; off <<= 1) {
        int t = (tid >= off) ? tmp[tid - off] : 0;
        __syncthreads();
        tmp[tid] += t;
        __syncthreads();
    }
    if (tid == 255) blockSums[blockIdx.x] = tmp[255];
    if (n < M) data[n] = tmp[tid] - v;  // exclusive within block (in-place)
}

__global__ __launch_bounds__(512) void k_scanB(int* __restrict__ blockSums, int nb) {
    __shared__ int tmp[512];
    int tid = threadIdx.x;
    int v = (tid < nb) ? blockSums[tid] : 0;
    tmp[tid] = v;
    __syncthreads();
    for (int off = 1; off < 512; off <<= 1) {
        int t = (tid >= off) ? tmp[tid - off] : 0;
        __syncthreads();
        tmp[tid] += t;
        __syncthreads();
    }
    if (tid < nb) blockSums[tid] = tmp[tid] - v;  // exclusive block offsets
}

__global__ __launch_bounds__(256) void k_scanC(int* __restrict__ data,
                                               const int* __restrict__ blockSums,
                                               int* __restrict__ bucketBase,
                                               int M, int T, int NB, int E) {
    int n = blockIdx.x * 256 + threadIdx.x;
    if (n >= M) return;
    int v = data[n] + blockSums[n >> 8];
    data[n] = v;                                   // global tile offsets
    if (n % T == 0) bucketBase[n / T] = v;         // bucket start = offset of its tile 0
    if (n == 0) bucketBase[NB] = E;
}

// ---------------- P3: scatter edges into buckets (LDS cursors, no global atomics) ----
// binned[pos] = (localNode << 24) | row   (row < 2^24, localNode < 256)
__global__ __launch_bounds__(1024) void k_binscatter(const int* __restrict__ edge,
                                                     const int* __restrict__ tileOff,
                                                     unsigned* __restrict__ binned,
                                                     int E, int T, int NB) {
    __shared__ int cur[NB_MAX];
    int tid = threadIdx.x;
    int t = blockIdx.x;
    for (int b = tid; b < NB; b += 1024) cur[b] = tileOff[b * T + t];
    __syncthreads();
    int tileBase = t * TILE_EDGES;
    for (int j = 0; j < TILE_EDGES / 1024; ++j) {
        int e = tileBase + j * 1024 + tid;
        if (e < E) {
            int r = edge[e];
            int c = edge[E + e];
            int pos = atomicAdd(&cur[c >> 8], 1);
            binned[pos] = ((unsigned)(c & (NPB - 1)) << 24) | (unsigned)r;
        }
    }
}

// ---------------- P4: per-bucket counting sort in LDS; emits CSR + deg + dinv -------
__global__ __launch_bounds__(512) void k_bucket(const unsigned* __restrict__ binned,
                                                const int* __restrict__ bucketBase,
                                                int* __restrict__ ssrc,
                                                int* __restrict__ offsets,
                                                int* __restrict__ deg,
                                                float* __restrict__ dinv, int N) {
    __shared__ int h[NPB], sc[NPB], cur[NPB];
    int tid = threadIdx.x;
    int b = blockIdx.x;
    int base = bucketBase[b];
    int cnt = bucketBase[b + 1] - base;
    if (tid < NPB) h[tid] = 0;
    __syncthreads();
    for (int i = tid; i < cnt; i += 512)
        atomicAdd(&h[binned[base + i] >> 24], 1);
    __syncthreads();
    // exclusive scan of h (256 entries, Hillis-Steele inclusive then subtract)
    if (tid < NPB) sc[tid] = h[tid];
    __syncthreads();
    for (int off = 1; off < NPB; off <<= 1) {
        int tv = (tid >= off && tid < NPB) ? sc[tid - off] : 0;
        __syncthreads();
        if (tid < NPB) sc[tid] += tv;
        __syncthreads();
    }
    if (tid < NPB) {
        int excl = sc[tid] - h[tid];
        cur[tid] = base + excl;
        int node = b * NPB + tid;
        if (node < N) {
            offsets[node] = base + excl;
            deg[node] = h[tid];
            dinv[node] = rsqrtf((float)(h[tid] + 1));  // +1 self-loop
        }
    }
    __syncthreads();
    for (int i = tid; i < cnt; i += 512) {
        unsigned v = binned[base + i];
        int pos = atomicAdd(&cur[v >> 24], 1);
        ssrc[pos] = (int)(v & 0xFFFFFFu);
    }
}

// ---------------- GEMM y = bf16((x @ W) * dinv[row]), W staged in LDS ----------------
__device__ inline void fma4(float4& acc, const float4 xv, const float4 w0,
                            const float4 w1, const float4 w2, const float4 w3) {
    acc.x = fmaf(xv.x, w0.x, fmaf(xv.y, w1.x, fmaf(xv.z, w2.x, fmaf(xv.w, w3.x, acc.x))));
    acc.y = fmaf(xv.x, w0.y, fmaf(xv.y, w1.y, fmaf(xv.z, w2.y, fmaf(xv.w, w3.y, acc.y))));
    acc.z = fmaf(xv.x, w0.z, fmaf(xv.y, w1.z, fmaf(xv.z, w2.z, fmaf(xv.w, w3.z, acc.z))));
    acc.w = fmaf(xv.x, w0.w, fmaf(xv.y, w1.w, fmaf(xv.z, w2.w, fmaf(xv.w, w3.w, acc.w))));
}

__device__ inline uint2 pack_bf16x4(float4 a) {
    union { uint2 u; bf16x2 h[2]; } p;
    p.h[0] = __float22bfloat162_rn(make_float2(a.x, a.y));
    p.h[1] = __float22bfloat162_rn(make_float2(a.z, a.w));
    return p.u;
}

__global__ __launch_bounds__(256) void k_gemm(const float* __restrict__ x,
                                              const float* __restrict__ W,
                                              const float* __restrict__ dinv,
                                              bf16* __restrict__ y, int N) {
    __shared__ float Ws[DF * DF];  // 64 KiB -> 2 blocks/CU
    for (int i = threadIdx.x; i < DF * DF / 4; i += 256)
        ((float4*)Ws)[i] = ((const float4*)W)[i];
    __syncthreads();

    const int fg = (threadIdx.x & 31) * 4;  // feature start [0,128)
    const int rl = (threadIdx.x >> 5) * 4;  // 8 groups x 4 rows = 32 rows/block

    for (int rowBase = blockIdx.x * 32; rowBase < N; rowBase += gridDim.x * 32) {
        int r0 = rowBase + rl;
        int c0 = min(r0 + 0, N - 1), c1 = min(r0 + 1, N - 1);
        int c2 = min(r0 + 2, N - 1), c3 = min(r0 + 3, N - 1);
        const float4* x0 = (const float4*)(x + (size_t)c0 * DF);
        const float4* x1 = (const float4*)(x + (size_t)c1 * DF);
        const float4* x2 = (const float4*)(x + (size_t)c2 * DF);
        const float4* x3 = (const float4*)(x + (size_t)c3 * DF);
        float4 a0 = {0, 0, 0, 0}, a1 = {0, 0, 0, 0}, a2 = {0, 0, 0, 0}, a3 = {0, 0, 0, 0};
        for (int k4 = 0; k4 < DF / 4; ++k4) {
            float4 xv0 = x0[k4], xv1 = x1[k4], xv2 = x2[k4], xv3 = x3[k4];
            int k = k4 * 4;
            float4 w0 = *(const float4*)(Ws + (k + 0) * DF + fg);
            float4 w1 = *(const float4*)(Ws + (k + 1) * DF + fg);
            float4 w2 = *(const float4*)(Ws + (k + 2) * DF + fg);
            float4 w3 = *(const float4*)(Ws + (k + 3) * DF + fg);
            fma4(a0, xv0, w0, w1, w2, w3);
            fma4(a1, xv1, w0, w1, w2, w3);
            fma4(a2, xv2, w0, w1, w2, w3);
            fma4(a3, xv3, w0, w1, w2, w3);
        }
        float d0 = dinv[c0], d1 = dinv[c1], d2 = dinv[c2], d3 = dinv[c3];
        a0.x *= d0; a0.y *= d0; a0.z *= d0; a0.w *= d0;
        a1.x *= d1; a1.y *= d1; a1.z *= d1; a1.w *= d1;
        a2.x *= d2; a2.y *= d2; a2.z *= d2; a2.w *= d2;
        a3.x *= d3; a3.y *= d3; a3.z *= d3; a3.w *= d3;
        if (r0 + 0 < N) *(uint2*)(y + (size_t)(r0 + 0) * DF + fg) = pack_bf16x4(a0);
        if (r0 + 1 < N) *(uint2*)(y + (size_t)(r0 + 1) * DF + fg) = pack_bf16x4(a1);
        if (r0 + 2 < N) *(uint2*)(y + (size_t)(r0 + 2) * DF + fg) = pack_bf16x4(a2);
        if (r0 + 3 < N) *(uint2*)(y + (size_t)(r0 + 3) * DF + fg) = pack_bf16x4(a3);
    }
}

// ---------------- gather-aggregate: one wave per target node ----------------
__global__ __launch_bounds__(256) void k_gather(const bf16x2* __restrict__ y,  // stride 64/row
                                                const int* __restrict__ ssrc,
                                                const int* __restrict__ offsets,
                                                const int* __restrict__ deg,
                                                const float* __restrict__ dinv,
                                                const float* __restrict__ b,
                                                float* __restrict__ out, int N) {
    int wave = (blockIdx.x * 256 + threadIdx.x) >> 6;  // 4 waves/block = 4 nodes
    int lane = threadIdx.x & 63;
    if (wave >= N) return;
    int c = wave;
    int start = offsets[c];
    int d = deg[c];

    // self-loop term: acc starts at y[c]
    float2 acc = __bfloat1622float2(y[(size_t)c * 64 + lane]);

    int i = 0;
    for (; i + 4 <= d; i += 4) {
        int r0 = ssrc[start + i + 0];
        int r1 = ssrc[start + i + 1];
        int r2 = ssrc[start + i + 2];
        int r3 = ssrc[start + i + 3];
        float2 v0 = __bfloat1622float2(y[(size_t)r0 * 64 + lane]);
        float2 v1 = __bfloat1622float2(y[(size_t)r1 * 64 + lane]);
        float2 v2 = __bfloat1622float2(y[(size_t)r2 * 64 + lane]);
        float2 v3 = __bfloat1622float2(y[(size_t)r3 * 64 + lane]);
        acc.x += (v0.x + v1.x) + (v2.x + v3.x);
        acc.y += (v0.y + v1.y) + (v2.y + v3.y);
    }
    for (; i < d; ++i) {
        int r0 = ssrc[start + i];
        float2 v0 = __bfloat1622float2(y[(size_t)r0 * 64 + lane]);
        acc.x += v0.x;
        acc.y += v0.y;
    }

    float dv = dinv[c];
    float2 bb = *(const float2*)(b + lane * 2);
    float2 o;
    o.x = fmaxf(fmaf(dv, acc.x, bb.x), 0.0f);
    o.y = fmaxf(fmaf(dv, acc.y, bb.y), 0.0f);
    *(float2*)(out + (size_t)c * DF + lane * 2) = o;
}

extern "C" void kernel_launch(void* const* d_in, const int* in_sizes, int n_in,
                              void* d_out, int out_size, void* d_ws, size_t ws_size,
                              hipStream_t stream) {
    const float* x    = (const float*)d_in[0];
    const int*   edge = (const int*)d_in[1];   // [2, E] flat: rows then cols
    const float* W    = (const float*)d_in[2];
    const float* b    = (const float*)d_in[3];
    float*       out  = (float*)d_out;

    const int N = in_sizes[0] / DF;   // 100000
    const int E = in_sizes[1] / 2;    // 3200000

    const int T  = (E + TILE_EDGES - 1) / TILE_EDGES;   // 196 bin tiles
    const int NB = (N + NPB - 1) / NPB;                 // 391 buckets (<= NB_MAX)
    const int M  = NB * T;                              // 76,636 counts

    // workspace layout (base is 16B-aligned)
    bf16*     y          = (bf16*)d_ws;              // N*128 bf16 (25.6 MB)
    int*      deg        = (int*)(y + (size_t)N * DF);
    float*    dinv       = (float*)(deg + N);
    int*      offsets    = (int*)(dinv + N);
    int*      bucketBase = offsets + N;              // NB+1 (pad 8)
    int*      blockSums  = bucketBase + NB + 8;      // 512 slots
    int*      counts     = blockSums + 512;          // M ints (~0.3 MB)
    unsigned* binned     = (unsigned*)(counts + M);  // E uints (12.8 MB)
    int*      ssrc       = (int*)(binned + E);       // E ints (12.8 MB)

    const int nbM = (M + 255) / 256;                 // 300 (<=512 required by scanB)

    k_binc<<<T, 1024, 0, stream>>>(edge + E, counts, E, T, NB);
    k_scanA<<<nbM, 256, 0, stream>>>(counts, blockSums, M);
    k_scanB<<<1, 512, 0, stream>>>(blockSums, nbM);
    k_scanC<<<nbM, 256, 0, stream>>>(counts, blockSums, bucketBase, M, T, NB, E);
    k_binscatter<<<T, 1024, 0, stream>>>(edge, counts, binned, E, T, NB);
    k_bucket<<<NB, 512, 0, stream>>>(binned, bucketBase, ssrc, offsets, deg, dinv, N);
    k_gemm<<<(N + 31) / 32, 256, 0, stream>>>(x, W, dinv, y, N);
    k_gather<<<(N + 3) / 4, 256, 0, stream>>>((const bf16x2*)y, ssrc, offsets, deg, dinv, b, out, N);
}

// Round 4
// 374.551 us; speedup vs baseline: 2.1496x; 1.0200x over previous
//
#include <hip/hip_runtime.h>
#include <hip/hip_bf16.h>
#include <math.h>

#define DF 128           // feature dim (both in and out)
#define TILE_EDGES 16384 // edges per bin tile (P1/P3)
#define NPB 256          // nodes per bucket (bucket = col >> 8)
#define NB_MAX 512       // max buckets (supports N <= 131072)

typedef __hip_bfloat16 bf16;
typedef __hip_bfloat162 bf16x2;

// ---------------- P1: per-tile LDS histogram over buckets ----------------
// counts laid out bucket-major: counts[b*T + t]
__global__ __launch_bounds__(1024) void k_binc(const int* __restrict__ col,
                                               int* __restrict__ counts,
                                               int E, int T, int NB) {
    __shared__ int h[NB_MAX];
    int tid = threadIdx.x;
    for (int i = tid; i < NB; i += 1024) h[i] = 0;
    __syncthreads();
    int tileBase = blockIdx.x * TILE_EDGES;
    for (int j = 0; j < TILE_EDGES / 1024; ++j) {
        int e = tileBase + j * 1024 + tid;
        if (e < E) atomicAdd(&h[col[e] >> 8], 1);
    }
    __syncthreads();
    for (int b = tid; b < NB; b += 1024)
        counts[b * T + blockIdx.x] = h[b];
}

// ---------------- scan of counts (M = NB*T elements), 3-phase ----------------
__global__ __launch_bounds__(256) void k_scanA(int* __restrict__ data,
                                               int* __restrict__ blockSums, int M) {
    __shared__ int tmp[256];
    int tid = threadIdx.x;
    int n = blockIdx.x * 256 + tid;
    int v = (n < M) ? data[n] : 0;
    tmp[tid] = v;
    __syncthreads();
    for (int off = 1; off < 256; off <<= 1) {
        int t = (tid >= off) ? tmp[tid - off] : 0;
        __syncthreads();
        tmp[tid] += t;
        __syncthreads();
    }
    if (tid == 255) blockSums[blockIdx.x] = tmp[255];
    if (n < M) data[n] = tmp[tid] - v;  // exclusive within block (in-place)
}

__global__ __launch_bounds__(512) void k_scanB(int* __restrict__ blockSums, int nb) {
    __shared__ int tmp[512];
    int tid = threadIdx.x;
    int v = (tid < nb) ? blockSums[tid] : 0;
    tmp[tid] = v;
    __syncthreads();
    for (int off = 1; off < 512; off <<= 1) {
        int t = (tid >= off) ? tmp[tid - off] : 0;
        __syncthreads();
        tmp[tid] += t;
        __syncthreads();
    }
    if (tid < nb) blockSums[tid] = tmp[tid] - v;  // exclusive block offsets
}

__global__ __launch_bounds__(256) void k_scanC(int* __restrict__ data,
                                               const int* __restrict__ blockSums,
                                               int* __restrict__ bucketBase,
                                               int M, int T, int NB, int E) {
    int n = blockIdx.x * 256 + threadIdx.x;
    if (n >= M) return;
    int v = data[n] + blockSums[n >> 8];
    data[n] = v;                                   // global tile offsets
    if (n % T == 0) bucketBase[n / T] = v;         // bucket start = offset of its tile 0
    if (n == 0) bucketBase[NB] = E;
}

// ---------------- P3: scatter edges into buckets (LDS cursors, no global atomics) ----
// binned[pos] = (localNode << 24) | row   (row < 2^24, localNode < 256)
__global__ __launch_bounds__(1024) void k_binscatter(const int* __restrict__ edge,
                                                     const int* __restrict__ tileOff,
                                                     unsigned* __restrict__ binned,
                                                     int E, int T, int NB) {
    __shared__ int cur[NB_MAX];
    int tid = threadIdx.x;
    int t = blockIdx.x;
    for (int b = tid; b < NB; b += 1024) cur[b] = tileOff[b * T + t];
    __syncthreads();
    int tileBase = t * TILE_EDGES;
    for (int j = 0; j < TILE_EDGES / 1024; ++j) {
        int e = tileBase + j * 1024 + tid;
        if (e < E) {
            int r = edge[e];
            int c = edge[E + e];
            int pos = atomicAdd(&cur[c >> 8], 1);
            binned[pos] = ((unsigned)(c & (NPB - 1)) << 24) | (unsigned)r;
        }
    }
}

// ---------------- P4: per-bucket counting sort in LDS; emits CSR + deg + dinv -------
__global__ __launch_bounds__(512) void k_bucket(const unsigned* __restrict__ binned,
                                                const int* __restrict__ bucketBase,
                                                int* __restrict__ ssrc,
                                                int* __restrict__ offsets,
                                                int* __restrict__ deg,
                                                float* __restrict__ dinv, int N) {
    __shared__ int h[NPB], sc[NPB], cur[NPB];
    int tid = threadIdx.x;
    int b = blockIdx.x;
    int base = bucketBase[b];
    int cnt = bucketBase[b + 1] - base;
    if (tid < NPB) h[tid] = 0;
    __syncthreads();
    for (int i = tid; i < cnt; i += 512)
        atomicAdd(&h[binned[base + i] >> 24], 1);
    __syncthreads();
    // exclusive scan of h (256 entries, Hillis-Steele inclusive then subtract)
    if (tid < NPB) sc[tid] = h[tid];
    __syncthreads();
    for (int off = 1; off < NPB; off <<= 1) {
        int tv = (tid >= off && tid < NPB) ? sc[tid - off] : 0;
        __syncthreads();
        if (tid < NPB) sc[tid] += tv;
        __syncthreads();
    }
    if (tid < NPB) {
        int excl = sc[tid] - h[tid];
        cur[tid] = base + excl;
        int node = b * NPB + tid;
        if (node < N) {
            offsets[node] = base + excl;
            deg[node] = h[tid];
            dinv[node] = rsqrtf((float)(h[tid] + 1));  // +1 self-loop
        }
    }
    __syncthreads();
    for (int i = tid; i < cnt; i += 512) {
        unsigned v = binned[base + i];
        int pos = atomicAdd(&cur[v >> 24], 1);
        ssrc[pos] = (int)(v & 0xFFFFFFu);
    }
}

// ---------------- GEMM y = bf16((x @ W) * dinv[row]), W staged in LDS ----------------
__device__ inline void fma4(float4& acc, const float4 xv, const float4 w0,
                            const float4 w1, const float4 w2, const float4 w3) {
    acc.x = fmaf(xv.x, w0.x, fmaf(xv.y, w1.x, fmaf(xv.z, w2.x, fmaf(xv.w, w3.x, acc.x))));
    acc.y = fmaf(xv.x, w0.y, fmaf(xv.y, w1.y, fmaf(xv.z, w2.y, fmaf(xv.w, w3.y, acc.y))));
    acc.z = fmaf(xv.x, w0.z, fmaf(xv.y, w1.z, fmaf(xv.z, w2.z, fmaf(xv.w, w3.z, acc.z))));
    acc.w = fmaf(xv.x, w0.w, fmaf(xv.y, w1.w, fmaf(xv.z, w2.w, fmaf(xv.w, w3.w, acc.w))));
}

__device__ inline uint2 pack_bf16x4(float4 a) {
    union { uint2 u; bf16x2 h[2]; } p;
    p.h[0] = __float22bfloat162_rn(make_float2(a.x, a.y));
    p.h[1] = __float22bfloat162_rn(make_float2(a.z, a.w));
    return p.u;
}

__global__ __launch_bounds__(256) void k_gemm(const float* __restrict__ x,
                                              const float* __restrict__ W,
                                              const float* __restrict__ dinv,
                                              bf16* __restrict__ y, int N) {
    __shared__ float Ws[DF * DF];  // 64 KiB -> 2 blocks/CU
    for (int i = threadIdx.x; i < DF * DF / 4; i += 256)
        ((float4*)Ws)[i] = ((const float4*)W)[i];
    __syncthreads();

    const int fg = (threadIdx.x & 31) * 4;  // feature start [0,128)
    const int rl = (threadIdx.x >> 5) * 4;  // 8 groups x 4 rows = 32 rows/block

    for (int rowBase = blockIdx.x * 32; rowBase < N; rowBase += gridDim.x * 32) {
        int r0 = rowBase + rl;
        int c0 = min(r0 + 0, N - 1), c1 = min(r0 + 1, N - 1);
        int c2 = min(r0 + 2, N - 1), c3 = min(r0 + 3, N - 1);
        const float4* x0 = (const float4*)(x + (size_t)c0 * DF);
        const float4* x1 = (const float4*)(x + (size_t)c1 * DF);
        const float4* x2 = (const float4*)(x + (size_t)c2 * DF);
        const float4* x3 = (const float4*)(x + (size_t)c3 * DF);
        float4 a0 = {0, 0, 0, 0}, a1 = {0, 0, 0, 0}, a2 = {0, 0, 0, 0}, a3 = {0, 0, 0, 0};
        for (int k4 = 0; k4 < DF / 4; ++k4) {
            float4 xv0 = x0[k4], xv1 = x1[k4], xv2 = x2[k4], xv3 = x3[k4];
            int k = k4 * 4;
            float4 w0 = *(const float4*)(Ws + (k + 0) * DF + fg);
            float4 w1 = *(const float4*)(Ws + (k + 1) * DF + fg);
            float4 w2 = *(const float4*)(Ws + (k + 2) * DF + fg);
            float4 w3 = *(const float4*)(Ws + (k + 3) * DF + fg);
            fma4(a0, xv0, w0, w1, w2, w3);
            fma4(a1, xv1, w0, w1, w2, w3);
            fma4(a2, xv2, w0, w1, w2, w3);
            fma4(a3, xv3, w0, w1, w2, w3);
        }
        float d0 = dinv[c0], d1 = dinv[c1], d2 = dinv[c2], d3 = dinv[c3];
        a0.x *= d0; a0.y *= d0; a0.z *= d0; a0.w *= d0;
        a1.x *= d1; a1.y *= d1; a1.z *= d1; a1.w *= d1;
        a2.x *= d2; a2.y *= d2; a2.z *= d2; a2.w *= d2;
        a3.x *= d3; a3.y *= d3; a3.z *= d3; a3.w *= d3;
        if (r0 + 0 < N) *(uint2*)(y + (size_t)(r0 + 0) * DF + fg) = pack_bf16x4(a0);
        if (r0 + 1 < N) *(uint2*)(y + (size_t)(r0 + 1) * DF + fg) = pack_bf16x4(a1);
        if (r0 + 2 < N) *(uint2*)(y + (size_t)(r0 + 2) * DF + fg) = pack_bf16x4(a2);
        if (r0 + 3 < N) *(uint2*)(y + (size_t)(r0 + 3) * DF + fg) = pack_bf16x4(a3);
    }
}

// ---------------- gather-aggregate: one wave per target node ----------------
// Lane-parallel index load (one coalesced load grabs the whole adjacency list,
// deg<=64 in the common case), then __shfl-broadcast each index and issue y-row
// loads in batches of 8 independent loads — no pointer chase in the hot loop.
__global__ __launch_bounds__(256) void k_gather(const bf16x2* __restrict__ y,  // stride 64/row
                                                const int* __restrict__ ssrc,
                                                const int* __restrict__ offsets,
                                                const int* __restrict__ deg,
                                                const float* __restrict__ dinv,
                                                const float* __restrict__ b,
                                                float* __restrict__ out, int N) {
    int wave = (blockIdx.x * 256 + threadIdx.x) >> 6;  // 4 waves/block = 4 nodes
    int lane = threadIdx.x & 63;
    if (wave >= N) return;
    int c = wave;
    int start = offsets[c];
    int d = deg[c];

    // self-loop term: acc starts at y[c]
    float2 acc = __bfloat1622float2(y[(size_t)c * 64 + lane]);

    for (int base = 0; base < d; base += 64) {
        int nb = min(64, d - base);                      // nb >= 1 here
        int idx = ssrc[start + base + min(lane, nb - 1)]; // coalesced, clamped
        int j = 0;
        for (; j + 8 <= nb; j += 8) {
            int r0 = __shfl(idx, j + 0);
            int r1 = __shfl(idx, j + 1);
            int r2 = __shfl(idx, j + 2);
            int r3 = __shfl(idx, j + 3);
            int r4 = __shfl(idx, j + 4);
            int r5 = __shfl(idx, j + 5);
            int r6 = __shfl(idx, j + 6);
            int r7 = __shfl(idx, j + 7);
            float2 v0 = __bfloat1622float2(y[(size_t)r0 * 64 + lane]);
            float2 v1 = __bfloat1622float2(y[(size_t)r1 * 64 + lane]);
            float2 v2 = __bfloat1622float2(y[(size_t)r2 * 64 + lane]);
            float2 v3 = __bfloat1622float2(y[(size_t)r3 * 64 + lane]);
            float2 v4 = __bfloat1622float2(y[(size_t)r4 * 64 + lane]);
            float2 v5 = __bfloat1622float2(y[(size_t)r5 * 64 + lane]);
            float2 v6 = __bfloat1622float2(y[(size_t)r6 * 64 + lane]);
            float2 v7 = __bfloat1622float2(y[(size_t)r7 * 64 + lane]);
            acc.x += ((v0.x + v1.x) + (v2.x + v3.x)) + ((v4.x + v5.x) + (v6.x + v7.x));
            acc.y += ((v0.y + v1.y) + (v2.y + v3.y)) + ((v4.y + v5.y) + (v6.y + v7.y));
        }
        for (; j < nb; ++j) {
            int r = __shfl(idx, j);
            float2 v = __bfloat1622float2(y[(size_t)r * 64 + lane]);
            acc.x += v.x;
            acc.y += v.y;
        }
    }

    float dv = dinv[c];
    float2 bb = *(const float2*)(b + lane * 2);
    float2 o;
    o.x = fmaxf(fmaf(dv, acc.x, bb.x), 0.0f);
    o.y = fmaxf(fmaf(dv, acc.y, bb.y), 0.0f);
    *(float2*)(out + (size_t)c * DF + lane * 2) = o;
}

extern "C" void kernel_launch(void* const* d_in, const int* in_sizes, int n_in,
                              void* d_out, int out_size, void* d_ws, size_t ws_size,
                              hipStream_t stream) {
    const float* x    = (const float*)d_in[0];
    const int*   edge = (const int*)d_in[1];   // [2, E] flat: rows then cols
    const float* W    = (const float*)d_in[2];
    const float* b    = (const float*)d_in[3];
    float*       out  = (float*)d_out;

    const int N = in_sizes[0] / DF;   // 100000
    const int E = in_sizes[1] / 2;    // 3200000

    const int T  = (E + TILE_EDGES - 1) / TILE_EDGES;   // 196 bin tiles
    const int NB = (N + NPB - 1) / NPB;                 // 391 buckets (<= NB_MAX)
    const int M  = NB * T;                              // 76,636 counts

    // workspace layout (base is 16B-aligned)
    bf16*     y          = (bf16*)d_ws;              // N*128 bf16 (25.6 MB)
    int*      deg        = (int*)(y + (size_t)N * DF);
    float*    dinv       = (float*)(deg + N);
    int*      offsets    = (int*)(dinv + N);
    int*      bucketBase = offsets + N;              // NB+1 (pad 8)
    int*      blockSums  = bucketBase + NB + 8;      // 512 slots
    int*      counts     = blockSums + 512;          // M ints (~0.3 MB)
    unsigned* binned     = (unsigned*)(counts + M);  // E uints (12.8 MB)
    int*      ssrc       = (int*)(binned + E);       // E ints (12.8 MB)

    const int nbM = (M + 255) / 256;                 // 300 (<=512 required by scanB)

    k_binc<<<T, 1024, 0, stream>>>(edge + E, counts, E, T, NB);
    k_scanA<<<nbM, 256, 0, stream>>>(counts, blockSums, M);
    k_scanB<<<1, 512, 0, stream>>>(blockSums, nbM);
    k_scanC<<<nbM, 256, 0, stream>>>(counts, blockSums, bucketBase, M, T, NB, E);
    k_binscatter<<<T, 1024, 0, stream>>>(edge, counts, binned, E, T, NB);
    k_bucket<<<NB, 512, 0, stream>>>(binned, bucketBase, ssrc, offsets, deg, dinv, N);
    k_gemm<<<(N + 31) / 32, 256, 0, stream>>>(x, W, dinv, y, N);
    k_gather<<<(N + 3) / 4, 256, 0, stream>>>((const bf16x2*)y, ssrc, offsets, deg, dinv, b, out, N);
}

// Round 5
// 324.487 us; speedup vs baseline: 2.4813x; 1.1543x over previous
//
#include <hip/hip_runtime.h>
#include <hip/hip_bf16.h>
#include <math.h>

#define DF 128           // feature dim (both in and out)
#define TILE_EDGES 6144  // edges per bin tile (P1/P3) -> 521 blocks (2.03/CU)
#define NPB 256          // nodes per bucket (bucket = col >> 8)
#define NB_MAX 512       // max buckets (supports N <= 131072)
#define KP 136           // padded K stride (bf16) for W^T LDS tile

typedef __hip_bfloat16 bf16;
typedef __hip_bfloat162 bf16x2;
typedef __attribute__((ext_vector_type(8))) short short8;
typedef __attribute__((ext_vector_type(4))) float f32x4;

__device__ inline short bf16bits(float f) {
    __hip_bfloat16 h = __float2bfloat16(f);
    return *reinterpret_cast<short*>(&h);
}

// ---------------- P1: per-tile LDS histogram over buckets ----------------
// counts laid out bucket-major: counts[b*T + t]
__global__ __launch_bounds__(512) void k_binc(const int* __restrict__ col,
                                              int* __restrict__ counts,
                                              int E, int T, int NB) {
    __shared__ int h[NB_MAX];
    int tid = threadIdx.x;
    for (int i = tid; i < NB; i += 512) h[i] = 0;
    __syncthreads();
    int tileBase = blockIdx.x * TILE_EDGES;
    for (int j = 0; j < TILE_EDGES / 512; ++j) {
        int e = tileBase + j * 512 + tid;
        if (e < E) atomicAdd(&h[col[e] >> 8], 1);
    }
    __syncthreads();
    for (int b = tid; b < NB; b += 512)
        counts[b * T + blockIdx.x] = h[b];
}

// ---------------- scan of counts (M = NB*T elements), 3-phase ----------------
__global__ __launch_bounds__(256) void k_scanA(int* __restrict__ data,
                                               int* __restrict__ blockSums, int M) {
    __shared__ int tmp[256];
    int tid = threadIdx.x;
    int n = blockIdx.x * 256 + tid;
    int v = (n < M) ? data[n] : 0;
    tmp[tid] = v;
    __syncthreads();
    for (int off = 1; off < 256; off <<= 1) {
        int t = (tid >= off) ? tmp[tid - off] : 0;
        __syncthreads();
        tmp[tid] += t;
        __syncthreads();
    }
    if (tid == 255) blockSums[blockIdx.x] = tmp[255];
    if (n < M) data[n] = tmp[tid] - v;  // exclusive within block (in-place)
}

__global__ __launch_bounds__(1024) void k_scanB(int* __restrict__ blockSums, int nb) {
    __shared__ int tmp[1024];
    int tid = threadIdx.x;
    int v = (tid < nb) ? blockSums[tid] : 0;
    tmp[tid] = v;
    __syncthreads();
    for (int off = 1; off < 1024; off <<= 1) {
        int t = (tid >= off) ? tmp[tid - off] : 0;
        __syncthreads();
        tmp[tid] += t;
        __syncthreads();
    }
    if (tid < nb) blockSums[tid] = tmp[tid] - v;  // exclusive block offsets
}

__global__ __launch_bounds__(256) void k_scanC(int* __restrict__ data,
                                               const int* __restrict__ blockSums,
                                               int* __restrict__ bucketBase,
                                               int M, int T, int NB, int E) {
    int n = blockIdx.x * 256 + threadIdx.x;
    if (n >= M) return;
    int v = data[n] + blockSums[n >> 8];
    data[n] = v;                                   // global tile offsets
    if (n % T == 0) bucketBase[n / T] = v;         // bucket start = offset of its tile 0
    if (n == 0) bucketBase[NB] = E;
}

// ---------------- P3: scatter edges into buckets (LDS cursors, no global atomics) ----
// binned[pos] = (localNode << 24) | row   (row < 2^24, localNode < 256)
__global__ __launch_bounds__(512) void k_binscatter(const int* __restrict__ edge,
                                                    const int* __restrict__ tileOff,
                                                    unsigned* __restrict__ binned,
                                                    int E, int T, int NB) {
    __shared__ int cur[NB_MAX];
    int tid = threadIdx.x;
    int t = blockIdx.x;
    for (int b = tid; b < NB; b += 512) cur[b] = tileOff[b * T + t];
    __syncthreads();
    int tileBase = t * TILE_EDGES;
    for (int j = 0; j < TILE_EDGES / 512; ++j) {
        int e = tileBase + j * 512 + tid;
        if (e < E) {
            int r = edge[e];
            int c = edge[E + e];
            int pos = atomicAdd(&cur[c >> 8], 1);
            binned[pos] = ((unsigned)(c & (NPB - 1)) << 24) | (unsigned)r;
        }
    }
}

// ---------------- P4: per-bucket counting sort in LDS; emits CSR + deg + dinv -------
__global__ __launch_bounds__(512) void k_bucket(const unsigned* __restrict__ binned,
                                                const int* __restrict__ bucketBase,
                                                int* __restrict__ ssrc,
                                                int* __restrict__ offsets,
                                                int* __restrict__ deg,
                                                float* __restrict__ dinv, int N) {
    __shared__ int h[NPB], sc[NPB], cur[NPB];
    int tid = threadIdx.x;
    int b = blockIdx.x;
    int base = bucketBase[b];
    int cnt = bucketBase[b + 1] - base;
    if (tid < NPB) h[tid] = 0;
    __syncthreads();
    for (int i = tid; i < cnt; i += 512)
        atomicAdd(&h[binned[base + i] >> 24], 1);
    __syncthreads();
    // exclusive scan of h (256 entries)
    if (tid < NPB) sc[tid] = h[tid];
    __syncthreads();
    for (int off = 1; off < NPB; off <<= 1) {
        int tv = (tid >= off && tid < NPB) ? sc[tid - off] : 0;
        __syncthreads();
        if (tid < NPB) sc[tid] += tv;
        __syncthreads();
    }
    if (tid < NPB) {
        int excl = sc[tid] - h[tid];
        cur[tid] = base + excl;
        int node = b * NPB + tid;
        if (node < N) {
            offsets[node] = base + excl;
            deg[node] = h[tid];
            dinv[node] = rsqrtf((float)(h[tid] + 1));  // +1 self-loop
        }
    }
    __syncthreads();
    for (int i = tid; i < cnt; i += 512) {
        unsigned v = binned[base + i];
        int pos = atomicAdd(&cur[v >> 24], 1);
        ssrc[pos] = (int)(v & 0xFFFFFFu);
    }
}

// ---------------- MFMA GEMM: y = bf16((x @ W) * dinv[row]) ----------------
// 16x16x32 bf16 MFMA. A-frag: A[m=lane&15][k=quad*8+j]; B-frag: B[k=quad*8+j][n=lane&15];
// C/D: col=lane&15, row=quad*4+reg (m89-verified layouts).
// W staged transposed (Wt[n][k], stride KP=136) in LDS -> ds_read_b128 per b-frag,
// bank-uniform (8 words/bank, zero excess conflict).
__global__ __launch_bounds__(256) void k_gemm(const float* __restrict__ x,
                                              const float* __restrict__ W,
                                              const float* __restrict__ dinv,
                                              bf16* __restrict__ y, int N) {
    __shared__ bf16 Wt[DF * KP];  // 34 KB
    int tid = threadIdx.x;
    // stage W -> Wt (transpose + f32->bf16)
    for (int i = tid; i < DF * (DF / 4); i += 256) {
        int k = i >> 5;           // 0..127
        int n4 = (i & 31) * 4;    // 0..124 step 4
        float4 w = *(const float4*)(W + k * DF + n4);
        Wt[(n4 + 0) * KP + k] = __float2bfloat16(w.x);
        Wt[(n4 + 1) * KP + k] = __float2bfloat16(w.y);
        Wt[(n4 + 2) * KP + k] = __float2bfloat16(w.z);
        Wt[(n4 + 3) * KP + k] = __float2bfloat16(w.w);
    }
    __syncthreads();

    const int wv = tid >> 6;       // wave 0..3
    const int lane = tid & 63;
    const int m16 = lane & 15;
    const int q = lane >> 4;       // quad 0..3
    const int rbase = blockIdx.x * 64 + wv * 16;
    const int arow = min(rbase + m16, N - 1);   // clamped A row for tail block

    f32x4 acc[8];
#pragma unroll
    for (int nt = 0; nt < 8; ++nt) acc[nt] = (f32x4){0.f, 0.f, 0.f, 0.f};

#pragma unroll
    for (int kc = 0; kc < 4; ++kc) {
        int k0 = kc * 32 + q * 8;
        float4 xa = *(const float4*)(x + (size_t)arow * DF + k0);
        float4 xb = *(const float4*)(x + (size_t)arow * DF + k0 + 4);
        short8 a;
        a[0] = bf16bits(xa.x); a[1] = bf16bits(xa.y);
        a[2] = bf16bits(xa.z); a[3] = bf16bits(xa.w);
        a[4] = bf16bits(xb.x); a[5] = bf16bits(xb.y);
        a[6] = bf16bits(xb.z); a[7] = bf16bits(xb.w);
#pragma unroll
        for (int nt = 0; nt < 8; ++nt) {
            short8 b = *(const short8*)(Wt + (nt * 16 + m16) * KP + k0);
            acc[nt] = __builtin_amdgcn_mfma_f32_16x16x32_bf16(a, b, acc[nt], 0, 0, 0);
        }
    }

    // epilogue: scale by dinv[row], store bf16
#pragma unroll
    for (int r = 0; r < 4; ++r) {
        int orow = rbase + q * 4 + r;
        if (orow < N) {
            float dv = dinv[orow];
#pragma unroll
            for (int nt = 0; nt < 8; ++nt) {
                y[(size_t)orow * DF + nt * 16 + m16] = __float2bfloat16(acc[nt][r] * dv);
            }
        }
    }
}

// ---------------- gather-aggregate: one wave per target node ----------------
// Lane-parallel index load + shfl broadcast; 8 independent y-row loads in flight.
__global__ __launch_bounds__(256) void k_gather(const bf16x2* __restrict__ y,  // stride 64/row
                                                const int* __restrict__ ssrc,
                                                const int* __restrict__ offsets,
                                                const int* __restrict__ deg,
                                                const float* __restrict__ dinv,
                                                const float* __restrict__ b,
                                                float* __restrict__ out, int N) {
    int wave = (blockIdx.x * 256 + threadIdx.x) >> 6;  // 4 waves/block = 4 nodes
    int lane = threadIdx.x & 63;
    if (wave >= N) return;
    int c = wave;
    int start = offsets[c];
    int d = deg[c];

    // self-loop term: acc starts at y[c]
    float2 acc = __bfloat1622float2(y[(size_t)c * 64 + lane]);

    for (int base = 0; base < d; base += 64) {
        int nb = min(64, d - base);                       // nb >= 1 here
        int idx = ssrc[start + base + min(lane, nb - 1)]; // coalesced, clamped
        int j = 0;
        for (; j + 8 <= nb; j += 8) {
            int r0 = __shfl(idx, j + 0);
            int r1 = __shfl(idx, j + 1);
            int r2 = __shfl(idx, j + 2);
            int r3 = __shfl(idx, j + 3);
            int r4 = __shfl(idx, j + 4);
            int r5 = __shfl(idx, j + 5);
            int r6 = __shfl(idx, j + 6);
            int r7 = __shfl(idx, j + 7);
            float2 v0 = __bfloat1622float2(y[(size_t)r0 * 64 + lane]);
            float2 v1 = __bfloat1622float2(y[(size_t)r1 * 64 + lane]);
            float2 v2 = __bfloat1622float2(y[(size_t)r2 * 64 + lane]);
            float2 v3 = __bfloat1622float2(y[(size_t)r3 * 64 + lane]);
            float2 v4 = __bfloat1622float2(y[(size_t)r4 * 64 + lane]);
            float2 v5 = __bfloat1622float2(y[(size_t)r5 * 64 + lane]);
            float2 v6 = __bfloat1622float2(y[(size_t)r6 * 64 + lane]);
            float2 v7 = __bfloat1622float2(y[(size_t)r7 * 64 + lane]);
            acc.x += ((v0.x + v1.x) + (v2.x + v3.x)) + ((v4.x + v5.x) + (v6.x + v7.x));
            acc.y += ((v0.y + v1.y) + (v2.y + v3.y)) + ((v4.y + v5.y) + (v6.y + v7.y));
        }
        for (; j < nb; ++j) {
            int r = __shfl(idx, j);
            float2 v = __bfloat1622float2(y[(size_t)r * 64 + lane]);
            acc.x += v.x;
            acc.y += v.y;
        }
    }

    float dv = dinv[c];
    float2 bb = *(const float2*)(b + lane * 2);
    float2 o;
    o.x = fmaxf(fmaf(dv, acc.x, bb.x), 0.0f);
    o.y = fmaxf(fmaf(dv, acc.y, bb.y), 0.0f);
    *(float2*)(out + (size_t)c * DF + lane * 2) = o;
}

extern "C" void kernel_launch(void* const* d_in, const int* in_sizes, int n_in,
                              void* d_out, int out_size, void* d_ws, size_t ws_size,
                              hipStream_t stream) {
    const float* x    = (const float*)d_in[0];
    const int*   edge = (const int*)d_in[1];   // [2, E] flat: rows then cols
    const float* W    = (const float*)d_in[2];
    const float* b    = (const float*)d_in[3];
    float*       out  = (float*)d_out;

    const int N = in_sizes[0] / DF;   // 100000
    const int E = in_sizes[1] / 2;    // 3200000

    const int T  = (E + TILE_EDGES - 1) / TILE_EDGES;   // 521 bin tiles
    const int NB = (N + NPB - 1) / NPB;                 // 391 buckets (<= NB_MAX)
    const int M  = NB * T;                              // ~203,711 counts

    // workspace layout (base is 16B-aligned)
    bf16*     y          = (bf16*)d_ws;              // N*128 bf16 (25.6 MB)
    int*      deg        = (int*)(y + (size_t)N * DF);
    float*    dinv       = (float*)(deg + N);
    int*      offsets    = (int*)(dinv + N);
    int*      bucketBase = offsets + N;              // NB+1 (pad 8)
    int*      blockSums  = bucketBase + NB + 8;      // 1024 slots
    int*      counts     = blockSums + 1024;         // M ints (~0.8 MB)
    unsigned* binned     = (unsigned*)(counts + M);  // E uints (12.8 MB)
    int*      ssrc       = (int*)(binned + E);       // E ints (12.8 MB)

    const int nbM = (M + 255) / 256;                 // 796 (<=1024 required by scanB)

    k_binc<<<T, 512, 0, stream>>>(edge + E, counts, E, T, NB);
    k_scanA<<<nbM, 256, 0, stream>>>(counts, blockSums, M);
    k_scanB<<<1, 1024, 0, stream>>>(blockSums, nbM);
    k_scanC<<<nbM, 256, 0, stream>>>(counts, blockSums, bucketBase, M, T, NB, E);
    k_binscatter<<<T, 512, 0, stream>>>(edge, counts, binned, E, T, NB);
    k_bucket<<<NB, 512, 0, stream>>>(binned, bucketBase, ssrc, offsets, deg, dinv, N);
    k_gemm<<<(N + 63) / 64, 256, 0, stream>>>(x, W, dinv, y, N);
    k_gather<<<(N + 3) / 4, 256, 0, stream>>>((const bf16x2*)y, ssrc, offsets, deg, dinv, b, out, N);
}